// Round 1
// baseline (393.618 us; speedup 1.0000x reference)
//
#include <hip/hip_runtime.h>
#include <math.h>

#define Bb 4
#define Ss 512
#define Hh 768
#define Vv 30522
#define Aa 200

typedef float f32x4 __attribute__((ext_vector_type(4)));
typedef short short8 __attribute__((ext_vector_type(8)));
typedef short short4v __attribute__((ext_vector_type(4)));
typedef __bf16 bf16x8 __attribute__((ext_vector_type(8)));

__device__ __forceinline__ unsigned short f2bf(float f) {
  union { float f; unsigned u; } v; v.f = f;
  unsigned r = v.u + 0x7FFFu + ((v.u >> 16) & 1u);
  return (unsigned short)(r >> 16);
}

// ---------------- K1: s[tok] = sum_a v_a * tanh(W1[a,:].h[tok] + b1[a]) ----
#define K1_TOK 8
__global__ __launch_bounds__(256) void k1_score(
    const float* __restrict__ hidden, const float* __restrict__ W1,
    const float* __restrict__ b1, const float* __restrict__ v_attn,
    float* __restrict__ s_buf)
{
  __shared__ float hsm[K1_TOK][Hh];
  __shared__ float part[K1_TOK][4];
  const int tid = threadIdx.x;
  const int tok0 = blockIdx.x * K1_TOK;
  #pragma unroll
  for (int i = 0; i < (K1_TOK * Hh / 4) / 256; ++i) {   // 6 iters
    int c = i * 256 + tid;
    int row = c / (Hh / 4);
    int col4 = c % (Hh / 4);
    f32x4 v = *reinterpret_cast<const f32x4*>(hidden + (size_t)(tok0 + row) * Hh + col4 * 4);
    *reinterpret_cast<f32x4*>(&hsm[row][col4 * 4]) = v;
  }
  __syncthreads();
  float acc[K1_TOK];
  #pragma unroll
  for (int t = 0; t < K1_TOK; ++t) acc[t] = 0.f;
  if (tid < Aa) {
    const float* wr = W1 + (size_t)tid * Hh;
    for (int h = 0; h < Hh; h += 4) {
      f32x4 w4 = *reinterpret_cast<const f32x4*>(wr + h);
      #pragma unroll
      for (int t = 0; t < K1_TOK; ++t) {
        f32x4 h4 = *reinterpret_cast<const f32x4*>(&hsm[t][h]);
        acc[t] += w4[0]*h4[0] + w4[1]*h4[1] + w4[2]*h4[2] + w4[3]*h4[3];
      }
    }
  }
  const int lane = tid & 63, wv = tid >> 6;
  #pragma unroll
  for (int t = 0; t < K1_TOK; ++t) {
    float x = (tid < Aa) ? v_attn[tid] * tanhf(acc[t] + b1[tid]) : 0.f;
    #pragma unroll
    for (int o = 32; o > 0; o >>= 1) x += __shfl_xor(x, o);
    if (lane == 0) part[t][wv] = x;
  }
  __syncthreads();
  if (tid < K1_TOK)
    s_buf[tok0 + tid] = part[tid][0] + part[tid][1] + part[tid][2] + part[tid][3];
}

// ---------------- K1.5: per-batch e = exp(s-max), prefix + suffix sums -----
#define ZLD 520
__global__ __launch_bounds__(256) void k15_pre(
    const float* __restrict__ s_buf, float* __restrict__ e_buf,
    float* __restrict__ zpref, float* __restrict__ zsuf)
{
  const int b = blockIdx.x, tid = threadIdx.x;
  __shared__ float se[512];
  __shared__ float bA[512], bB[512];
  __shared__ float pm[4];
  float v0 = s_buf[b * 512 + tid], v1 = s_buf[b * 512 + 256 + tid];
  float m = fmaxf(v0, v1);
  #pragma unroll
  for (int o = 32; o > 0; o >>= 1) m = fmaxf(m, __shfl_xor(m, o));
  if ((tid & 63) == 0) pm[tid >> 6] = m;
  __syncthreads();
  float M = fmaxf(fmaxf(pm[0], pm[1]), fmaxf(pm[2], pm[3]));
  float e0 = expf(v0 - M), e1 = expf(v1 - M);
  se[tid] = e0; se[tid + 256] = e1;
  e_buf[b * 512 + tid] = e0; e_buf[b * 512 + 256 + tid] = e1;
  bA[tid] = e0; bA[tid + 256] = e1;
  __syncthreads();
  float* src = bA; float* dst = bB;
  for (int off = 1; off < 512; off <<= 1) {  // forward inclusive scan
    for (int i = tid; i < 512; i += 256)
      dst[i] = src[i] + ((i >= off) ? src[i - off] : 0.f);
    __syncthreads();
    float* t = src; src = dst; dst = t;
  }
  if (tid == 0) zpref[b * ZLD] = 0.f;
  zpref[b * ZLD + 1 + tid] = src[tid];
  zpref[b * ZLD + 257 + tid] = src[tid + 256];
  __syncthreads();
  src[tid] = se[tid]; src[tid + 256] = se[tid + 256];
  __syncthreads();
  for (int off = 1; off < 512; off <<= 1) {  // backward inclusive scan (no cancellation)
    for (int i = tid; i < 512; i += 256)
      dst[i] = src[i] + ((i + off < 512) ? src[i + off] : 0.f);
    __syncthreads();
    float* t = src; src = dst; dst = t;
  }
  zsuf[b * ZLD + tid] = src[tid];
  zsuf[b * ZLD + 256 + tid] = src[tid + 256];
  if (tid == 0) zsuf[b * ZLD + 512] = 0.f;
}

// ---------------- K2a: per-64-chunk partial sums of e_k * h[k][f] ----------
__global__ __launch_bounds__(256) void k2a_part(
    const float* __restrict__ hidden, const float* __restrict__ e_buf,
    float* __restrict__ spart)
{
  const int bid = blockIdx.x;
  const int fc = bid % 3, c = (bid / 3) % 8, b = bid / 24;
  const int f = fc * 256 + threadIdx.x;
  float acc = 0.f;
  for (int kk = 0; kk < 64; ++kk) {
    int k = c * 64 + kk;
    acc += e_buf[b * 512 + k] * hidden[((size_t)(b * 512 + k)) * Hh + f];
  }
  spart[((size_t)b * 8 + c) * Hh + f] = acc;
}

// ---------------- K2c: scan -> hidd (fp32 to d_out, bf16 to ws) ------------
__global__ __launch_bounds__(256) void k2c_scan(
    const float* __restrict__ hidden, const float* __restrict__ e_buf,
    const float* __restrict__ zpref, const float* __restrict__ zsuf,
    const float* __restrict__ spart, const int* __restrict__ ptype,
    float* __restrict__ out_hidd, unsigned short* __restrict__ hbf)
{
  const int bid = blockIdx.x;
  const int fc = bid % 3, jc = (bid / 3) % 8, b = bid / 24;
  const int f = fc * 256 + threadIdx.x;
  const int type = ptype[b];
  const float* Sp = spart + (size_t)b * 8 * Hh;
  const float* Zp = zpref + b * ZLD;
  const float* Zs = zsuf + b * ZLD;
  const size_t hbase = (size_t)b * 512 * Hh + f;
  if (type == 0) {
    float run = 0.f;
    for (int c = 0; c < jc; ++c) run += Sp[c * Hh + f];
    for (int jj = 0; jj < 64; ++jj) {
      int j = jc * 64 + jj;
      float ev = e_buf[b * 512 + j];
      float h = hidden[hbase + (size_t)j * Hh];
      run += ev * h;
      float val = run / (Zp[j + 1] * (float)(j + 1));
      out_hidd[hbase + (size_t)j * Hh] = val;
      hbf[hbase + (size_t)j * Hh] = f2bf(val);
    }
  } else if (type == 1) {
    float run = 0.f;
    for (int c = jc + 1; c < 8; ++c) run += Sp[c * Hh + f];
    for (int jj = 63; jj >= 0; --jj) {
      int j = jc * 64 + jj;
      float ev = e_buf[b * 512 + j];
      float h = hidden[hbase + (size_t)j * Hh];
      run += ev * h;
      float val = run / (Zs[j] * (float)(512 - j));
      out_hidd[hbase + (size_t)j * Hh] = val;
      hbf[hbase + (size_t)j * Hh] = f2bf(val);
    }
  } else {
    float T = 0.f;
    for (int c = 0; c < 8; ++c) T += Sp[c * Hh + f];
    float Ztot = Zp[512];
    for (int jj = 0; jj < 64; ++jj) {
      int j = jc * 64 + jj;
      float ev = e_buf[b * 512 + j];
      float h = hidden[hbase + (size_t)j * Hh];
      float val = (T - ev * h) / ((Ztot - ev) * 511.0f);
      out_hidd[hbase + (size_t)j * Hh] = val;
      hbf[hbase + (size_t)j * Hh] = f2bf(val);
    }
  }
}

// ---------------- GEMM: C[m,n] = sum_k A[m,k]*B[n,k] + bias[n] -------------
// A bf16 [M][K], B fp32 [N][K] (converted on the fly), C fp32 [M][N]
#define GBM 128
#define GBN 128
#define GBK 64
__global__ __launch_bounds__(256) void gemm_bt(
    const unsigned short* __restrict__ Abf, const float* __restrict__ Bsrc,
    const float* __restrict__ bias, float* __restrict__ C,
    const int M, const int N, const int K, const int ntm)
{
  __shared__ unsigned short As[GBM * GBK];
  __shared__ unsigned short Bs[GBN * GBK];
  const int tid = threadIdx.x;
  const int total = gridDim.x;
  int bid = blockIdx.x;
  if ((total & 7) == 0) bid = (bid & 7) * (total >> 3) + (bid >> 3);  // XCD-chunked
  const int bm = bid % ntm;          // bn-major: A tiles stream, B tile reused per XCD
  const int bn = bid / ntm;
  const int lane = tid & 63;
  const int wv = tid >> 6;
  const int wr = wv >> 1, wc = wv & 1;
  const int r15 = lane & 15, kg = lane >> 4;

  f32x4 acc[4][4];
  #pragma unroll
  for (int m = 0; m < 4; ++m)
    #pragma unroll
    for (int n = 0; n < 4; ++n)
      #pragma unroll
      for (int r = 0; r < 4; ++r) acc[m][n][r] = 0.f;

  for (int kt = 0; kt < K; kt += GBK) {
    __syncthreads();
    #pragma unroll
    for (int i = 0; i < 4; ++i) {           // A: 128x64 bf16, 16B chunks
      int c = i * 256 + tid;
      int row = c >> 3, col8 = c & 7;
      short8 v = *reinterpret_cast<const short8*>(Abf + (size_t)(bm * GBM + row) * K + kt + col8 * 8);
      int idx = (row * GBK + col8 * 8) ^ ((row & 7) << 3);   // XOR swizzle (16B units)
      *reinterpret_cast<short8*>(&As[idx]) = v;
    }
    #pragma unroll
    for (int i = 0; i < 8; ++i) {           // B: 128x64 fp32 -> bf16
      int c = i * 256 + tid;
      int row = c >> 4, col4 = c & 15;
      int nsrc = bn * GBN + row; nsrc = nsrc < N ? nsrc : N - 1;
      f32x4 v = *reinterpret_cast<const f32x4*>(Bsrc + (size_t)nsrc * K + kt + col4 * 4);
      short4v p;
      #pragma unroll
      for (int q = 0; q < 4; ++q) p[q] = (short)f2bf(v[q]);
      int idx = (row * GBK + col4 * 4) ^ ((row & 7) << 3);
      *reinterpret_cast<short4v*>(&Bs[idx]) = p;
    }
    __syncthreads();
    #pragma unroll
    for (int kk = 0; kk < GBK / 32; ++kk) {
      bf16x8 af[4], bf[4];
      #pragma unroll
      for (int m = 0; m < 4; ++m) {
        int row = wr * 64 + m * 16 + r15;
        int col = kk * 32 + kg * 8;
        af[m] = *reinterpret_cast<const bf16x8*>(&As[(row * GBK + col) ^ ((row & 7) << 3)]);
      }
      #pragma unroll
      for (int n = 0; n < 4; ++n) {
        int row = wc * 64 + n * 16 + r15;
        int col = kk * 32 + kg * 8;
        bf[n] = *reinterpret_cast<const bf16x8*>(&Bs[(row * GBK + col) ^ ((row & 7) << 3)]);
      }
      #pragma unroll
      for (int m = 0; m < 4; ++m)
        #pragma unroll
        for (int n = 0; n < 4; ++n)
          acc[m][n] = __builtin_amdgcn_mfma_f32_16x16x32_bf16(af[m], bf[n], acc[m][n], 0, 0, 0);
    }
  }
  #pragma unroll
  for (int n = 0; n < 4; ++n) {
    int col = bn * GBN + wc * 64 + n * 16 + r15;
    if (col < N) {
      float bv = bias[col];
      #pragma unroll
      for (int m = 0; m < 4; ++m) {
        int rbase = bm * GBM + wr * 64 + m * 16 + kg * 4;
        #pragma unroll
        for (int r = 0; r < 4; ++r)
          C[(size_t)(rbase + r) * N + col] = acc[m][n][r] + bv;
      }
    }
  }
}

// ---------------- K3b: exact GELU + LayerNorm -> xn (bf16) -----------------
__global__ __launch_bounds__(256) void k3b_geluln(
    const float* __restrict__ x, const float* __restrict__ gam,
    const float* __restrict__ bet, unsigned short* __restrict__ xnbf)
{
  const int row = blockIdx.x, tid = threadIdx.x;
  __shared__ float part[4];
  float g[3];
  float s = 0.f;
  #pragma unroll
  for (int i = 0; i < 3; ++i) {
    float xv = x[(size_t)row * Hh + tid + 256 * i];
    float t = 0.5f * xv * (1.f + erff(xv * 0.70710678118654752f));
    g[i] = t; s += t;
  }
  #pragma unroll
  for (int o = 32; o > 0; o >>= 1) s += __shfl_xor(s, o);
  if ((tid & 63) == 0) part[tid >> 6] = s;
  __syncthreads();
  float mu = (part[0] + part[1] + part[2] + part[3]) * (1.f / 768.f);
  __syncthreads();
  float vs = 0.f;
  #pragma unroll
  for (int i = 0; i < 3; ++i) { float d = g[i] - mu; vs += d * d; }
  #pragma unroll
  for (int o = 32; o > 0; o >>= 1) vs += __shfl_xor(vs, o);
  if ((tid & 63) == 0) part[tid >> 6] = vs;
  __syncthreads();
  float var = (part[0] + part[1] + part[2] + part[3]) * (1.f / 768.f);
  float inv = 1.0f / sqrtf(var + 1e-12f);
  #pragma unroll
  for (int i = 0; i < 3; ++i) {
    int f = tid + 256 * i;
    xnbf[(size_t)row * Hh + f] = f2bf((g[i] - mu) * inv * gam[f] + bet[f]);
  }
}

extern "C" void kernel_launch(void* const* d_in, const int* in_sizes, int n_in,
                              void* d_out, int out_size, void* d_ws, size_t ws_size,
                              hipStream_t stream)
{
  const float* hidden = (const float*)d_in[0];
  const int*   ptype  = (const int*)d_in[1];
  const float* W1     = (const float*)d_in[2];
  const float* b1     = (const float*)d_in[3];
  const float* vat    = (const float*)d_in[4];
  const float* Wfc    = (const float*)d_in[5];
  const float* bfc    = (const float*)d_in[6];
  const float* lng    = (const float*)d_in[7];
  const float* lnb    = (const float*)d_in[8];
  const float* Wout   = (const float*)d_in[9];
  const float* bout   = (const float*)d_in[10];

  float* out_hidd = (float*)d_out;
  float* out_logits = out_hidd + (size_t)Bb * Ss * Hh;

  float* ws = (float*)d_ws;
  float* s_buf = ws;                               // 2048
  float* e_buf = ws + 2048;                        // 2048
  float* zpref = ws + 4096;                        // 4*520
  float* zsuf  = ws + 4096 + 4 * ZLD;              // 4*520
  float* spart = ws + 8256;                        // 4*8*768 = 24576
  float* xbuf  = ws + 32832;                       // 2048*768 fp32
  unsigned short* hbf  = (unsigned short*)(ws + 1605696);           // 2048*768 bf16
  unsigned short* xnbf = (unsigned short*)(ws + 1605696 + 786432);  // 2048*768 bf16

  k1_score<<<dim3(Bb * Ss / K1_TOK), dim3(256), 0, stream>>>(hidden, W1, b1, vat, s_buf);
  k15_pre<<<dim3(Bb), dim3(256), 0, stream>>>(s_buf, e_buf, zpref, zsuf);
  k2a_part<<<dim3(Bb * 8 * 3), dim3(256), 0, stream>>>(hidden, e_buf, spart);
  k2c_scan<<<dim3(Bb * 8 * 3), dim3(256), 0, stream>>>(hidden, e_buf, zpref, zsuf,
                                                       spart, ptype, out_hidd, hbf);
  gemm_bt<<<dim3((2048 / GBM) * (Hh / GBN)), dim3(256), 0, stream>>>(
      hbf, Wfc, bfc, xbuf, 2048, Hh, Hh, 2048 / GBM);
  k3b_geluln<<<dim3(2048), dim3(256), 0, stream>>>(xbuf, lng, lnb, xnbf);
  gemm_bt<<<dim3((2048 / GBM) * ((Vv + GBN - 1) / GBN)), dim3(256), 0, stream>>>(
      xnbf, Wout, bout, out_logits, 2048, Vv, Hh, 2048 / GBM);
}

// Round 2
// 348.218 us; speedup vs baseline: 1.1304x; 1.1304x over previous
//
#include <hip/hip_runtime.h>
#include <math.h>

#define Bb 4
#define Ss 512
#define Hh 768
#define Vv 30522
#define Aa 200

typedef float f32x4 __attribute__((ext_vector_type(4)));
typedef short short8 __attribute__((ext_vector_type(8)));
typedef short short4v __attribute__((ext_vector_type(4)));
typedef __bf16 bf16x8 __attribute__((ext_vector_type(8)));

__device__ __forceinline__ unsigned short f2bf(float f) {
  union { float f; unsigned u; } v; v.f = f;
  unsigned r = v.u + 0x7FFFu + ((v.u >> 16) & 1u);
  return (unsigned short)(r >> 16);
}

__device__ __forceinline__ void gload16(const void* g, void* l) {
  __builtin_amdgcn_global_load_lds(
      (const __attribute__((address_space(1))) void*)g,
      (__attribute__((address_space(3))) void*)l, 16, 0, 0);
}

// ---------------- K0: fp32 -> bf16 weight conversion -----------------------
__global__ __launch_bounds__(256) void wconv(
    const float* __restrict__ src, unsigned short* __restrict__ dst, int n4)
{
  int i = blockIdx.x * 256 + threadIdx.x;
  const int stride = gridDim.x * 256;
  for (; i < n4; i += stride) {
    f32x4 v = *reinterpret_cast<const f32x4*>(src + (size_t)i * 4);
    short4v p;
    #pragma unroll
    for (int q = 0; q < 4; ++q) p[q] = (short)f2bf(v[q]);
    *reinterpret_cast<short4v*>(dst + (size_t)i * 4) = p;
  }
}

// ---------------- K1: s[tok] = sum_a v_a * tanh(W1[a,:].h[tok] + b1[a]) ----
#define K1_TOK 8
__global__ __launch_bounds__(256) void k1_score(
    const float* __restrict__ hidden, const float* __restrict__ W1,
    const float* __restrict__ b1, const float* __restrict__ v_attn,
    float* __restrict__ s_buf)
{
  __shared__ float hsm[K1_TOK][Hh];
  __shared__ float part[K1_TOK][4];
  const int tid = threadIdx.x;
  const int tok0 = blockIdx.x * K1_TOK;
  #pragma unroll
  for (int i = 0; i < (K1_TOK * Hh / 4) / 256; ++i) {   // 6 iters
    int c = i * 256 + tid;
    int row = c / (Hh / 4);
    int col4 = c % (Hh / 4);
    f32x4 v = *reinterpret_cast<const f32x4*>(hidden + (size_t)(tok0 + row) * Hh + col4 * 4);
    *reinterpret_cast<f32x4*>(&hsm[row][col4 * 4]) = v;
  }
  __syncthreads();
  float acc[K1_TOK];
  #pragma unroll
  for (int t = 0; t < K1_TOK; ++t) acc[t] = 0.f;
  if (tid < Aa) {
    const float* wr = W1 + (size_t)tid * Hh;
    for (int h = 0; h < Hh; h += 4) {
      f32x4 w4 = *reinterpret_cast<const f32x4*>(wr + h);
      #pragma unroll
      for (int t = 0; t < K1_TOK; ++t) {
        f32x4 h4 = *reinterpret_cast<const f32x4*>(&hsm[t][h]);
        acc[t] += w4[0]*h4[0] + w4[1]*h4[1] + w4[2]*h4[2] + w4[3]*h4[3];
      }
    }
  }
  const int lane = tid & 63, wv = tid >> 6;
  #pragma unroll
  for (int t = 0; t < K1_TOK; ++t) {
    float x = (tid < Aa) ? v_attn[tid] * tanhf(acc[t] + b1[tid]) : 0.f;
    #pragma unroll
    for (int o = 32; o > 0; o >>= 1) x += __shfl_xor(x, o);
    if (lane == 0) part[t][wv] = x;
  }
  __syncthreads();
  if (tid < K1_TOK)
    s_buf[tok0 + tid] = part[tid][0] + part[tid][1] + part[tid][2] + part[tid][3];
}

// ---------------- K1.5: per-batch e = exp(s-max), prefix + suffix sums -----
#define ZLD 520
__global__ __launch_bounds__(256) void k15_pre(
    const float* __restrict__ s_buf, float* __restrict__ e_buf,
    float* __restrict__ zpref, float* __restrict__ zsuf)
{
  const int b = blockIdx.x, tid = threadIdx.x;
  __shared__ float se[512];
  __shared__ float bA[512], bB[512];
  __shared__ float pm[4];
  float v0 = s_buf[b * 512 + tid], v1 = s_buf[b * 512 + 256 + tid];
  float m = fmaxf(v0, v1);
  #pragma unroll
  for (int o = 32; o > 0; o >>= 1) m = fmaxf(m, __shfl_xor(m, o));
  if ((tid & 63) == 0) pm[tid >> 6] = m;
  __syncthreads();
  float M = fmaxf(fmaxf(pm[0], pm[1]), fmaxf(pm[2], pm[3]));
  float e0 = expf(v0 - M), e1 = expf(v1 - M);
  se[tid] = e0; se[tid + 256] = e1;
  e_buf[b * 512 + tid] = e0; e_buf[b * 512 + 256 + tid] = e1;
  bA[tid] = e0; bA[tid + 256] = e1;
  __syncthreads();
  float* src = bA; float* dst = bB;
  for (int off = 1; off < 512; off <<= 1) {  // forward inclusive scan
    for (int i = tid; i < 512; i += 256)
      dst[i] = src[i] + ((i >= off) ? src[i - off] : 0.f);
    __syncthreads();
    float* t = src; src = dst; dst = t;
  }
  if (tid == 0) zpref[b * ZLD] = 0.f;
  zpref[b * ZLD + 1 + tid] = src[tid];
  zpref[b * ZLD + 257 + tid] = src[tid + 256];
  __syncthreads();
  src[tid] = se[tid]; src[tid + 256] = se[tid + 256];
  __syncthreads();
  for (int off = 1; off < 512; off <<= 1) {  // backward inclusive scan (no cancellation)
    for (int i = tid; i < 512; i += 256)
      dst[i] = src[i] + ((i + off < 512) ? src[i + off] : 0.f);
    __syncthreads();
    float* t = src; src = dst; dst = t;
  }
  zsuf[b * ZLD + tid] = src[tid];
  zsuf[b * ZLD + 256 + tid] = src[tid + 256];
  if (tid == 0) zsuf[b * ZLD + 512] = 0.f;
}

// ---------------- K2a: per-64-chunk partial sums of e_k * h[k][f] ----------
__global__ __launch_bounds__(256) void k2a_part(
    const float* __restrict__ hidden, const float* __restrict__ e_buf,
    float* __restrict__ spart)
{
  const int bid = blockIdx.x;
  const int fc = bid % 3, c = (bid / 3) % 8, b = bid / 24;
  const int f = fc * 256 + threadIdx.x;
  float acc = 0.f;
  for (int kk = 0; kk < 64; ++kk) {
    int k = c * 64 + kk;
    acc += e_buf[b * 512 + k] * hidden[((size_t)(b * 512 + k)) * Hh + f];
  }
  spart[((size_t)b * 8 + c) * Hh + f] = acc;
}

// ---------------- K2c: scan -> hidd (fp32 to d_out, bf16 to ws) ------------
__global__ __launch_bounds__(256) void k2c_scan(
    const float* __restrict__ hidden, const float* __restrict__ e_buf,
    const float* __restrict__ zpref, const float* __restrict__ zsuf,
    const float* __restrict__ spart, const int* __restrict__ ptype,
    float* __restrict__ out_hidd, unsigned short* __restrict__ hbf)
{
  const int bid = blockIdx.x;
  const int fc = bid % 3, jc = (bid / 3) % 8, b = bid / 24;
  const int f = fc * 256 + threadIdx.x;
  const int type = ptype[b];
  const float* Sp = spart + (size_t)b * 8 * Hh;
  const float* Zp = zpref + b * ZLD;
  const float* Zs = zsuf + b * ZLD;
  const size_t hbase = (size_t)b * 512 * Hh + f;
  if (type == 0) {
    float run = 0.f;
    for (int c = 0; c < jc; ++c) run += Sp[c * Hh + f];
    for (int jj = 0; jj < 64; ++jj) {
      int j = jc * 64 + jj;
      float ev = e_buf[b * 512 + j];
      float h = hidden[hbase + (size_t)j * Hh];
      run += ev * h;
      float val = run / (Zp[j + 1] * (float)(j + 1));
      out_hidd[hbase + (size_t)j * Hh] = val;
      hbf[hbase + (size_t)j * Hh] = f2bf(val);
    }
  } else if (type == 1) {
    float run = 0.f;
    for (int c = jc + 1; c < 8; ++c) run += Sp[c * Hh + f];
    for (int jj = 63; jj >= 0; --jj) {
      int j = jc * 64 + jj;
      float ev = e_buf[b * 512 + j];
      float h = hidden[hbase + (size_t)j * Hh];
      run += ev * h;
      float val = run / (Zs[j] * (float)(512 - j));
      out_hidd[hbase + (size_t)j * Hh] = val;
      hbf[hbase + (size_t)j * Hh] = f2bf(val);
    }
  } else {
    float T = 0.f;
    for (int c = 0; c < 8; ++c) T += Sp[c * Hh + f];
    float Ztot = Zp[512];
    for (int jj = 0; jj < 64; ++jj) {
      int j = jc * 64 + jj;
      float ev = e_buf[b * 512 + j];
      float h = hidden[hbase + (size_t)j * Hh];
      float val = (T - ev * h) / ((Ztot - ev) * 511.0f);
      out_hidd[hbase + (size_t)j * Hh] = val;
      hbf[hbase + (size_t)j * Hh] = f2bf(val);
    }
  }
}

// ---------------- GEMM (bf16 A, bf16 B): C[m,n] = sum_k A[m,k]*B[n,k]+bias -
// global_load_lds staging, linear LDS dest, inverse-swizzled global source,
// swizzled ds_read_b128 fragment reads (16B-chunk XOR: chunk' = chunk ^ (row&7))
#define GBM 128
#define GBN 128
#define GBK 64
__global__ __launch_bounds__(256) void gemm_bb(
    const unsigned short* __restrict__ Abf, const unsigned short* __restrict__ Bbf,
    const float* __restrict__ bias, float* __restrict__ C,
    const int M, const int N, const int K, const int ntm)
{
  __shared__ unsigned short As[GBM * GBK];
  __shared__ unsigned short Bs[GBN * GBK];
  const int tid = threadIdx.x;
  const int total = gridDim.x;
  int bid = blockIdx.x;
  if ((total & 7) == 0) bid = (bid & 7) * (total >> 3) + (bid >> 3);  // XCD-chunked
  const int bm = bid % ntm;          // bn-major: B tile reused within XCD chunk
  const int bn = bid / ntm;
  const int lane = tid & 63;
  const int wv = tid >> 6;
  const int wr = wv >> 1, wc = wv & 1;
  const int r15 = lane & 15, kg = lane >> 4;

  // precompute staging pointers: LDS chunk qq holds global 16B-chunk (qq&7)^(r&7)
  const unsigned short* ga[4];
  const unsigned short* gb[4];
  unsigned short* la[4];
  unsigned short* lb[4];
  #pragma unroll
  for (int i = 0; i < 4; ++i) {
    int qq = i * 256 + tid;
    int r = qq >> 3;
    int ks = (qq & 7) ^ (r & 7);
    ga[i] = Abf + (size_t)(bm * GBM + r) * K + ks * 8;
    int rowb = bn * GBN + r; rowb = rowb < N ? rowb : N - 1;
    gb[i] = Bbf + (size_t)rowb * K + ks * 8;
    la[i] = &As[qq * 8];
    lb[i] = &Bs[qq * 8];
  }

  f32x4 acc[4][4];
  #pragma unroll
  for (int m = 0; m < 4; ++m)
    #pragma unroll
    for (int n = 0; n < 4; ++n)
      #pragma unroll
      for (int r = 0; r < 4; ++r) acc[m][n][r] = 0.f;

  for (int kt = 0; kt < K; kt += GBK) {
    __syncthreads();
    #pragma unroll
    for (int i = 0; i < 4; ++i) gload16(ga[i] + kt, la[i]);
    #pragma unroll
    for (int i = 0; i < 4; ++i) gload16(gb[i] + kt, lb[i]);
    __syncthreads();
    #pragma unroll
    for (int kk = 0; kk < GBK / 32; ++kk) {
      bf16x8 af[4], bf[4];
      #pragma unroll
      for (int m = 0; m < 4; ++m) {
        int ra = wr * 64 + m * 16 + r15;
        int ck = ((kk << 2) | kg) ^ (ra & 7);
        af[m] = *reinterpret_cast<const bf16x8*>(&As[ra * GBK + ck * 8]);
      }
      #pragma unroll
      for (int n = 0; n < 4; ++n) {
        int rb = wc * 64 + n * 16 + r15;
        int ck = ((kk << 2) | kg) ^ (rb & 7);
        bf[n] = *reinterpret_cast<const bf16x8*>(&Bs[rb * GBK + ck * 8]);
      }
      #pragma unroll
      for (int m = 0; m < 4; ++m)
        #pragma unroll
        for (int n = 0; n < 4; ++n)
          acc[m][n] = __builtin_amdgcn_mfma_f32_16x16x32_bf16(af[m], bf[n], acc[m][n], 0, 0, 0);
    }
  }
  #pragma unroll
  for (int n = 0; n < 4; ++n) {
    int col = bn * GBN + wc * 64 + n * 16 + r15;
    if (col < N) {
      float bv = bias[col];
      #pragma unroll
      for (int m = 0; m < 4; ++m) {
        int rbase = bm * GBM + wr * 64 + m * 16 + kg * 4;
        #pragma unroll
        for (int r = 0; r < 4; ++r)
          C[(size_t)(rbase + r) * N + col] = acc[m][n][r] + bv;
      }
    }
  }
}

// ---------------- fallback GEMM (fp32 B, on-the-fly convert) ---------------
__global__ __launch_bounds__(256) void gemm_bt(
    const unsigned short* __restrict__ Abf, const float* __restrict__ Bsrc,
    const float* __restrict__ bias, float* __restrict__ C,
    const int M, const int N, const int K, const int ntm)
{
  __shared__ unsigned short As[GBM * GBK];
  __shared__ unsigned short Bs[GBN * GBK];
  const int tid = threadIdx.x;
  const int total = gridDim.x;
  int bid = blockIdx.x;
  if ((total & 7) == 0) bid = (bid & 7) * (total >> 3) + (bid >> 3);
  const int bm = bid % ntm;
  const int bn = bid / ntm;
  const int lane = tid & 63;
  const int wv = tid >> 6;
  const int wr = wv >> 1, wc = wv & 1;
  const int r15 = lane & 15, kg = lane >> 4;

  f32x4 acc[4][4];
  #pragma unroll
  for (int m = 0; m < 4; ++m)
    #pragma unroll
    for (int n = 0; n < 4; ++n)
      #pragma unroll
      for (int r = 0; r < 4; ++r) acc[m][n][r] = 0.f;

  for (int kt = 0; kt < K; kt += GBK) {
    __syncthreads();
    #pragma unroll
    for (int i = 0; i < 4; ++i) {
      int c = i * 256 + tid;
      int row = c >> 3, col8 = c & 7;
      short8 v = *reinterpret_cast<const short8*>(Abf + (size_t)(bm * GBM + row) * K + kt + col8 * 8);
      int idx = (row * GBK + col8 * 8) ^ ((row & 7) << 3);
      *reinterpret_cast<short8*>(&As[idx]) = v;
    }
    #pragma unroll
    for (int i = 0; i < 8; ++i) {
      int c = i * 256 + tid;
      int row = c >> 4, col4 = c & 15;
      int nsrc = bn * GBN + row; nsrc = nsrc < N ? nsrc : N - 1;
      f32x4 v = *reinterpret_cast<const f32x4*>(Bsrc + (size_t)nsrc * K + kt + col4 * 4);
      short4v p;
      #pragma unroll
      for (int q = 0; q < 4; ++q) p[q] = (short)f2bf(v[q]);
      int idx = (row * GBK + col4 * 4) ^ ((row & 7) << 3);
      *reinterpret_cast<short4v*>(&Bs[idx]) = p;
    }
    __syncthreads();
    #pragma unroll
    for (int kk = 0; kk < GBK / 32; ++kk) {
      bf16x8 af[4], bf[4];
      #pragma unroll
      for (int m = 0; m < 4; ++m) {
        int row = wr * 64 + m * 16 + r15;
        int col = kk * 32 + kg * 8;
        af[m] = *reinterpret_cast<const bf16x8*>(&As[(row * GBK + col) ^ ((row & 7) << 3)]);
      }
      #pragma unroll
      for (int n = 0; n < 4; ++n) {
        int row = wc * 64 + n * 16 + r15;
        int col = kk * 32 + kg * 8;
        bf[n] = *reinterpret_cast<const bf16x8*>(&Bs[(row * GBK + col) ^ ((row & 7) << 3)]);
      }
      #pragma unroll
      for (int m = 0; m < 4; ++m)
        #pragma unroll
        for (int n = 0; n < 4; ++n)
          acc[m][n] = __builtin_amdgcn_mfma_f32_16x16x32_bf16(af[m], bf[n], acc[m][n], 0, 0, 0);
    }
  }
  #pragma unroll
  for (int n = 0; n < 4; ++n) {
    int col = bn * GBN + wc * 64 + n * 16 + r15;
    if (col < N) {
      float bv = bias[col];
      #pragma unroll
      for (int m = 0; m < 4; ++m) {
        int rbase = bm * GBM + wr * 64 + m * 16 + kg * 4;
        #pragma unroll
        for (int r = 0; r < 4; ++r)
          C[(size_t)(rbase + r) * N + col] = acc[m][n][r] + bv;
      }
    }
  }
}

// ---------------- K3b: exact GELU + LayerNorm -> xn (bf16) -----------------
__global__ __launch_bounds__(256) void k3b_geluln(
    const float* __restrict__ x, const float* __restrict__ gam,
    const float* __restrict__ bet, unsigned short* __restrict__ xnbf)
{
  const int row = blockIdx.x, tid = threadIdx.x;
  __shared__ float part[4];
  float g[3];
  float s = 0.f;
  #pragma unroll
  for (int i = 0; i < 3; ++i) {
    float xv = x[(size_t)row * Hh + tid + 256 * i];
    float t = 0.5f * xv * (1.f + erff(xv * 0.70710678118654752f));
    g[i] = t; s += t;
  }
  #pragma unroll
  for (int o = 32; o > 0; o >>= 1) s += __shfl_xor(s, o);
  if ((tid & 63) == 0) part[tid >> 6] = s;
  __syncthreads();
  float mu = (part[0] + part[1] + part[2] + part[3]) * (1.f / 768.f);
  __syncthreads();
  float vs = 0.f;
  #pragma unroll
  for (int i = 0; i < 3; ++i) { float d = g[i] - mu; vs += d * d; }
  #pragma unroll
  for (int o = 32; o > 0; o >>= 1) vs += __shfl_xor(vs, o);
  if ((tid & 63) == 0) part[tid >> 6] = vs;
  __syncthreads();
  float var = (part[0] + part[1] + part[2] + part[3]) * (1.f / 768.f);
  float inv = 1.0f / sqrtf(var + 1e-12f);
  #pragma unroll
  for (int i = 0; i < 3; ++i) {
    int f = tid + 256 * i;
    xnbf[(size_t)row * Hh + f] = f2bf((g[i] - mu) * inv * gam[f] + bet[f]);
  }
}

extern "C" void kernel_launch(void* const* d_in, const int* in_sizes, int n_in,
                              void* d_out, int out_size, void* d_ws, size_t ws_size,
                              hipStream_t stream)
{
  const float* hidden = (const float*)d_in[0];
  const int*   ptype  = (const int*)d_in[1];
  const float* W1     = (const float*)d_in[2];
  const float* b1     = (const float*)d_in[3];
  const float* vat    = (const float*)d_in[4];
  const float* Wfc    = (const float*)d_in[5];
  const float* bfc    = (const float*)d_in[6];
  const float* lng    = (const float*)d_in[7];
  const float* lnb    = (const float*)d_in[8];
  const float* Wout   = (const float*)d_in[9];
  const float* bout   = (const float*)d_in[10];

  float* out_hidd = (float*)d_out;
  float* out_logits = out_hidd + (size_t)Bb * Ss * Hh;

  float* ws = (float*)d_ws;
  float* s_buf = ws;                               // 2048
  float* e_buf = ws + 2048;                        // 2048
  float* zpref = ws + 4096;                        // 4*520
  float* zsuf  = ws + 4096 + 4 * ZLD;              // 4*520
  float* spart = ws + 8256;                        // 4*8*768
  float* xbuf  = ws + 32832;                       // 2048*768 fp32
  unsigned short* hbf  = (unsigned short*)(ws + 1605696);           // 2048*768 bf16
  unsigned short* xnbf = (unsigned short*)(ws + 1605696 + 786432);  // 2048*768 bf16
  unsigned short* wfcb = (unsigned short*)((char*)d_ws + 12714240); // 768*768 bf16
  unsigned short* woutb = (unsigned short*)((char*)d_ws + 13893888);// 30522*768 bf16
  const size_t need = 13893888 + (size_t)Vv * Hh * 2;               // ~60.8 MB

  const bool pre = ws_size >= need;

  k1_score<<<dim3(Bb * Ss / K1_TOK), dim3(256), 0, stream>>>(hidden, W1, b1, vat, s_buf);
  k15_pre<<<dim3(Bb), dim3(256), 0, stream>>>(s_buf, e_buf, zpref, zsuf);
  if (pre) {
    wconv<<<dim3(256), dim3(256), 0, stream>>>(Wfc, wfcb, Hh * Hh / 4);
    wconv<<<dim3(2048), dim3(256), 0, stream>>>(Wout, woutb, Vv * Hh / 4);
  }
  k2a_part<<<dim3(Bb * 8 * 3), dim3(256), 0, stream>>>(hidden, e_buf, spart);
  k2c_scan<<<dim3(Bb * 8 * 3), dim3(256), 0, stream>>>(hidden, e_buf, zpref, zsuf,
                                                       spart, ptype, out_hidd, hbf);
  if (pre) {
    gemm_bb<<<dim3((2048 / GBM) * (Hh / GBN)), dim3(256), 0, stream>>>(
        hbf, wfcb, bfc, xbuf, 2048, Hh, Hh, 2048 / GBM);
  } else {
    gemm_bt<<<dim3((2048 / GBM) * (Hh / GBN)), dim3(256), 0, stream>>>(
        hbf, Wfc, bfc, xbuf, 2048, Hh, Hh, 2048 / GBM);
  }
  k3b_geluln<<<dim3(2048), dim3(256), 0, stream>>>(xbuf, lng, lnb, xnbf);
  if (pre) {
    gemm_bb<<<dim3((2048 / GBM) * ((Vv + GBN - 1) / GBN)), dim3(256), 0, stream>>>(
        xnbf, woutb, bout, out_logits, 2048, Vv, Hh, 2048 / GBM);
  } else {
    gemm_bt<<<dim3((2048 / GBM) * ((Vv + GBN - 1) / GBN)), dim3(256), 0, stream>>>(
        xnbf, Wout, bout, out_logits, 2048, Vv, Hh, 2048 / GBM);
  }
}